// Round 7
// baseline (212.958 us; speedup 1.0000x reference)
//
#include <hip/hip_runtime.h>
#include <hip/hip_bf16.h>
#include <cstdint>

#define BB 4
#define HH 8
#define LL 2048
#define DD 64
#define SK 40
#define NT 40
#define BHN (BB*HH)            // 32
#define SCALE 0.125f
#define CHUNK 128
#define NCH (LL/CHUNK)         // 16
#define USPL 5
#define UPB (NT/USPL)          // 8 u-rows per k3a block

// workspace layout in floats
#define WS_M    0                          // [BHN*LL]            = 65536
#define WS_SUB  (WS_M + BHN*LL)            // [BHN*64*DD]         = 131072
#define WS_CTX  (WS_SUB + BHN*64*DD)       // (unused)
#define WS_PM   (WS_CTX + BHN*NT*DD)       // [BHN*NT*NCH]        = 20480
#define WS_PSUM (WS_PM + BHN*NT*NCH)       // [BHN*NT*NCH]        = 20480
#define WS_PACC (WS_PSUM + BHN*NT*NCH)     // [BHN*NT*NCH*DD]     = 1310720
#define WS_TOP  (WS_PACC + BHN*NT*NCH*DD)  // int [BHN*NT]

static __device__ __forceinline__ float4 f4add(float4 a, float4 b) {
    float4 r; r.x = a.x + b.x; r.y = a.y + b.y; r.z = a.z + b.z; r.w = a.w + b.w; return r;
}

// ---------------- K1: M[b,h,l] = max_s(QK) - sum_s(QK)/L ----------------
// (unchanged from R6 — known 43 us; restructure deferred)
__global__ __launch_bounds__(256) void k1_M(const float* __restrict__ Q,
                                            const float* __restrict__ K,
                                            const int* __restrict__ isamp,
                                            float* __restrict__ M) {
    int bid  = blockIdx.x;
    int swz  = (bid & 7) * (BHN * LL / 4 / 8) + (bid >> 3);   // bijective, 16384%8==0
    int wid  = swz * 4 + (threadIdx.x >> 6);   // = bh*LL + l
    int lane = threadIdx.x & 63;
    int bh   = wid >> 11;
    int l    = wid & (LL - 1);
    int g    = lane >> 4;
    int e    = lane & 15;

    float4 q = reinterpret_cast<const float4*>(Q + (size_t)wid * DD)[e];
    const float* Kbh = K + (size_t)bh * LL * DD;
    const int* irow = isamp + l * SK;

    int idxs[SK / 4];
#pragma unroll
    for (int p = 0; p < SK / 4; p++) idxs[p] = irow[p * 4 + g];

    float mx = -INFINITY, sm = 0.f;
#pragma unroll
    for (int b = 0; b < 2; b++) {
        float4 kv[5];
#pragma unroll
        for (int i = 0; i < 5; i++)
            kv[i] = reinterpret_cast<const float4*>(Kbh + (size_t)idxs[b * 5 + i] * DD)[e];
        float dd[5];
#pragma unroll
        for (int i = 0; i < 5; i++)
            dd[i] = q.x * kv[i].x + q.y * kv[i].y + q.z * kv[i].z + q.w * kv[i].w;
#pragma unroll
        for (int i = 0; i < 5; i++) {
            float d = dd[i];
            d += __shfl_xor(d, 1);
            d += __shfl_xor(d, 2);
            d += __shfl_xor(d, 4);
            d += __shfl_xor(d, 8);
            mx = fmaxf(mx, d);
            sm += d;
        }
    }
    mx = fmaxf(mx, __shfl_xor(mx, 16));
    mx = fmaxf(mx, __shfl_xor(mx, 32));
    sm += __shfl_xor(sm, 16);
    sm += __shfl_xor(sm, 32);
    if (lane == 0) M[wid] = mx - sm * (1.0f / (float)LL);
}

// ---------------- K2: top-40 per (b,h); register-resident, one wave ----------------
__global__ __launch_bounds__(64) void k2_topk(const float* __restrict__ M,
                                              int* __restrict__ Mtop) {
    int bh = blockIdx.x, lane = threadIdx.x;
    const float* Mb = M + (size_t)bh * LL;
    unsigned long long key[32];
#pragma unroll
    for (int j = 0; j < 32; j++) {
        int i = lane + j * 64;
        unsigned u = __float_as_uint(Mb[i]);
        u = (u & 0x80000000u) ? ~u : (u | 0x80000000u);
        key[j] = ((unsigned long long)u << 32) | (unsigned)(~i);
    }
    unsigned long long winner = 0ull;
    for (int t = 0; t < NT; t++) {
        unsigned long long best = 0ull;
#pragma unroll
        for (int j = 0; j < 32; j++) {
            unsigned long long k = key[j];
            k = (k == winner) ? 0ull : k;
            key[j] = k;
            best = (k > best) ? k : best;
        }
#pragma unroll
        for (int off = 32; off; off >>= 1) {
            unsigned long long o = __shfl_xor(best, off);
            best = (o > best) ? o : best;
        }
        winner = best;
        if (lane == 0) Mtop[bh * NT + t] = (int)(~(unsigned)(best & 0xFFFFFFFFull));
    }
}

// ---------------- K3a: chunked partial attention, USPL=5 (8 u/block) ----------------
// grid 2560, 256 thr, ~6KB LDS -> 8 blocks/CU = 32 waves/CU.
__global__ __launch_bounds__(256) void k3a_partial(const float* __restrict__ Q,
                                                   const float* __restrict__ K,
                                                   const float* __restrict__ V,
                                                   const int* __restrict__ Mtop,
                                                   float* __restrict__ pm,
                                                   float* __restrict__ psum,
                                                   float* __restrict__ pacc) {
    __shared__ float q_lds[UPB * DD];      // 2 KB
    __shared__ float s_lds[UPB][CHUNK];    // 4 KB
    __shared__ int   qi_lds[UPB];
    int bid = blockIdx.x;
    int swz = (bid & 7) * (BHN * NCH * USPL / 8) + (bid >> 3);   // 2560%8==0
    int bh  = swz / (NCH * USPL);
    int rem = swz % (NCH * USPL);
    int ch  = rem / USPL;                  // consecutive blocks share ch -> K/V L2 reuse
    int u0  = (rem % USPL) * UPB;
    int ck  = ch * CHUNK;
    int tid = threadIdx.x;

    if (tid < UPB) qi_lds[tid] = Mtop[bh * NT + u0 + tid];
    __syncthreads();
    for (int c = tid; c < UPB * 16; c += 256) {
        int u = c >> 4, j = c & 15;
        reinterpret_cast<float4*>(q_lds)[c] =
            reinterpret_cast<const float4*>(Q + ((size_t)bh * LL + qi_lds[u]) * DD)[j];
    }
    __syncthreads();

    // scores: thread pair (half 0/1) per key; K half-row in registers
    int k    = ck + (tid >> 1);
    int half = tid & 1;
    const float4* krow = reinterpret_cast<const float4*>(K + ((size_t)bh * LL + k) * DD) + half * 8;
    float4 kreg[8];
#pragma unroll
    for (int j = 0; j < 8; j++) kreg[j] = krow[j];
#pragma unroll
    for (int u = 0; u < UPB; u++) {
        const float4* q4 = reinterpret_cast<const float4*>(q_lds + u * DD) + half * 8;
        float d = 0.f;
#pragma unroll
        for (int j = 0; j < 8; j++) {
            float4 a = q4[j], b = kreg[j];
            d += a.x * b.x + a.y * b.y + a.z * b.z + a.w * b.w;
        }
        d += __shfl_xor(d, 1);
        float s = (k <= qi_lds[u]) ? d * SCALE : -INFINITY;
        if (half == 0) s_lds[u][k - ck] = s;
    }
    __syncthreads();

    // per-u local max + expsum; wave w owns u = w + 4*uu (uu < 2)
    int w = tid >> 6, lane = tid & 63;
#pragma unroll
    for (int uu = 0; uu < UPB / 4; uu++) {
        int u = w + uu * 4;
        float s0 = s_lds[u][lane], s1 = s_lds[u][lane + 64];
        float m = fmaxf(s0, s1);
#pragma unroll
        for (int off = 32; off; off >>= 1) m = fmaxf(m, __shfl_xor(m, off));
        float e0 = (s0 == -INFINITY) ? 0.f : __expf(s0 - m);
        float e1 = (s1 == -INFINITY) ? 0.f : __expf(s1 - m);
        s_lds[u][lane] = e0;
        s_lds[u][lane + 64] = e1;
        float smv = e0 + e1;
#pragma unroll
        for (int off = 32; off; off >>= 1) smv += __shfl_xor(smv, off);
        if (lane == 0) {
            size_t rg = (size_t)bh * NT + u0 + u;
            pm  [rg * NCH + ch] = m;
            psum[rg * NCH + ch] = smv;
        }
    }
    __syncthreads();

    // partial PV: wave w owns u = w + 4*uu, lane = d
    float acc[UPB / 4] = {};
    const float* vbase = V + ((size_t)bh * LL + ck) * DD + lane;
#pragma unroll 4
    for (int kk = 0; kk < CHUNK; kk++) {
        float v = vbase[(size_t)kk * DD];
#pragma unroll
        for (int uu = 0; uu < UPB / 4; uu++)
            acc[uu] += s_lds[w + uu * 4][kk] * v;
    }
#pragma unroll
    for (int uu = 0; uu < UPB / 4; uu++) {
        size_t rg = (size_t)bh * NT + u0 + w + uu * 4;
        pacc[(rg * NCH + ch) * DD + lane] = acc[uu];
    }
}

// ---------------- K4a: 32-row chunk sums of V (256 thr, float4, full occ) ----------------
// block = bh*64 + j; thread (d4 = t&15, rg = t>>4) sums rows rg*2, rg*2+1.
__global__ __launch_bounds__(256) void k4a_sub(const float* __restrict__ V,
                                               float* __restrict__ sub) {
    __shared__ float4 part[16][16];
    int blk = blockIdx.x;
    int t = threadIdx.x;
    int d4 = t & 15, rg = t >> 4;
    const float4* v4 = reinterpret_cast<const float4*>(V) + (size_t)blk * 32 * 16 + (size_t)rg * 2 * 16 + d4;
    float4 a = v4[0], b = v4[16];
    part[rg][d4] = f4add(a, b);
    __syncthreads();
#pragma unroll
    for (int step = 8; step; step >>= 1) {
        if (rg < step) part[rg][d4] = f4add(part[rg][d4], part[rg + step][d4]);
        __syncthreads();
    }
    if (rg == 0)
        reinterpret_cast<float4*>(sub)[(size_t)blk * 16 + d4] = part[0][d4];
}

// ---------------- K4b: scan + fused merge/scatter ----------------
// block = bh*64 + j. Phase 1: inclusive cumsum of rows [j*32, j*32+32) into out.
// Phase 2 (after barrier; __syncthreads drains vmem): overwrite the Mtop rows
// belonging to this 32-row chunk with the merged attention context.
__global__ __launch_bounds__(256) void k4b_scan(const float* __restrict__ V,
                                                const float* __restrict__ sub,
                                                const float* __restrict__ pm,
                                                const float* __restrict__ psum,
                                                const float* __restrict__ pacc,
                                                const int* __restrict__ Mtop,
                                                float* __restrict__ out) {
    __shared__ float4 plds[16][16];
    int blk = blockIdx.x;
    int bh = blk >> 6, j = blk & 63;
    int t = threadIdx.x;
    int d4 = t & 15, rg = t >> 4;

    // chunk offset: sum of previous chunk sums
    const float4* sub4 = reinterpret_cast<const float4*>(sub) + (size_t)(bh * 64) * 16 + d4;
    float4 off = {0.f, 0.f, 0.f, 0.f};
    for (int p = 0; p < j; p++) off = f4add(off, sub4[(size_t)p * 16]);

    // local 2-row segment
    const float4* v4 = reinterpret_cast<const float4*>(V) + (size_t)blk * 32 * 16 + (size_t)rg * 2 * 16 + d4;
    float4 a = v4[0], b = v4[16];
    plds[rg][d4] = f4add(a, b);
    __syncthreads();
    float4 ex = {0.f, 0.f, 0.f, 0.f};
    for (int p = 0; p < rg; p++) ex = f4add(ex, plds[p][d4]);

    float4 r0 = f4add(f4add(off, ex), a);
    float4 r1 = f4add(r0, b);
    float4* o4 = reinterpret_cast<float4*>(out) + (size_t)blk * 32 * 16 + (size_t)rg * 2 * 16 + d4;
    o4[0] = r0;
    o4[16] = r1;
    __syncthreads();   // drains the stores above before the overwrite below

    // fused merge + scatter for u-rows whose qi lands in this chunk
    if (t < DD) {
        for (int u = 0; u < NT; u++) {
            int qi = Mtop[bh * NT + u];
            if ((qi >> 5) != j) continue;
            size_t row = (size_t)bh * NT + u;
            float pmv[NCH];
            float m = -INFINITY;
#pragma unroll
            for (int i = 0; i < NCH; i++) {
                pmv[i] = pm[row * NCH + i];
                m = fmaxf(m, pmv[i]);
            }
            float Z = 0.f, acc = 0.f;
#pragma unroll
            for (int i = 0; i < NCH; i++) {
                float sc = (pmv[i] == -INFINITY) ? 0.f : __expf(pmv[i] - m);
                Z   += psum[row * NCH + i] * sc;
                acc += pacc[(row * NCH + i) * DD + t] * sc;
            }
            out[((size_t)bh * LL + qi) * DD + t] = acc / Z;
        }
    }
}

extern "C" void kernel_launch(void* const* d_in, const int* in_sizes, int n_in,
                              void* d_out, int out_size, void* d_ws, size_t ws_size,
                              hipStream_t stream) {
    const float* Q = (const float*)d_in[0];
    const float* K = (const float*)d_in[1];
    const float* V = (const float*)d_in[2];
    const int* isamp = (const int*)d_in[3];
    float* ws   = (float*)d_ws;
    float* M    = ws + WS_M;
    float* sub  = ws + WS_SUB;
    float* pm   = ws + WS_PM;
    float* psum = ws + WS_PSUM;
    float* pacc = ws + WS_PACC;
    int*   Mtop = (int*)(ws + WS_TOP);
    float* out  = (float*)d_out;

    k1_M       <<<BHN * LL / 4,      256, 0, stream>>>(Q, K, isamp, M);
    k2_topk    <<<BHN,                64, 0, stream>>>(M, Mtop);
    k3a_partial<<<BHN * NCH * USPL,  256, 0, stream>>>(Q, K, V, Mtop, pm, psum, pacc);
    k4a_sub    <<<BHN * 64,          256, 0, stream>>>(V, sub);
    k4b_scan   <<<BHN * 64,          256, 0, stream>>>(V, sub, pm, psum, pacc, Mtop, out);
}

// Round 9
// 176.912 us; speedup vs baseline: 1.2038x; 1.2038x over previous
//
#include <hip/hip_runtime.h>
#include <hip/hip_bf16.h>
#include <cstdint>

#define BB 4
#define HH 8
#define LL 2048
#define DD 64
#define SK 40
#define NT 40
#define BHN (BB*HH)            // 32
#define SCALE 0.125f
#define CHUNK 128
#define NCH (LL/CHUNK)         // 16
#define USPL 2
#define UPB (NT/USPL)          // 20 u-rows per k3a block

// workspace layout in floats
#define WS_M    0                          // [BHN*LL]            = 65536
#define WS_SUB  (WS_M + BHN*LL)            // [BHN*64*DD]         = 131072
#define WS_CTX  (WS_SUB + BHN*64*DD)       // (unused)
#define WS_PM   (WS_CTX + BHN*NT*DD)       // [BHN*NT*NCH]        = 20480
#define WS_PSUM (WS_PM + BHN*NT*NCH)       // [BHN*NT*NCH]        = 20480
#define WS_PACC (WS_PSUM + BHN*NT*NCH)     // [BHN*NT*NCH*DD]     = 1310720
#define WS_TOP  (WS_PACC + BHN*NT*NCH*DD)  // int [BHN*NT]

#define K1_BLOCKS (BHN * LL / 4)   // 16384
#define K4A_BLOCKS (BHN * 64)      // 2048
#define K4B_BLOCKS (BHN * 64)      // 2048

static __device__ __forceinline__ float4 f4add(float4 a, float4 b) {
    float4 r; r.x = a.x + b.x; r.y = a.y + b.y; r.z = a.z + b.z; r.w = a.w + b.w; return r;
}

// ================= F1: [k1 || k4a] =================
// blocks [0, 16384): k1 — M[b,h,l] = max_s(QK) - sum_s(QK)/L  (XCD-swizzled)
// blocks [16384, 18432): k4a — 32-row chunk sums of V (independent of k1)
__global__ __launch_bounds__(256) void f1_m_sub(const float* __restrict__ Q,
                                                const float* __restrict__ K,
                                                const int* __restrict__ isamp,
                                                const float* __restrict__ V,
                                                float* __restrict__ M,
                                                float* __restrict__ sub) {
    int bid = blockIdx.x;
    if (bid < K1_BLOCKS) {
        // ---- k1 body (unchanged) ----
        int swz  = (bid & 7) * (K1_BLOCKS / 8) + (bid >> 3);
        int wid  = swz * 4 + (threadIdx.x >> 6);
        int lane = threadIdx.x & 63;
        int bh   = wid >> 11;
        int l    = wid & (LL - 1);
        int g    = lane >> 4;
        int e    = lane & 15;

        float4 q = reinterpret_cast<const float4*>(Q + (size_t)wid * DD)[e];
        const float* Kbh = K + (size_t)bh * LL * DD;
        const int* irow = isamp + l * SK;

        int idxs[SK / 4];
#pragma unroll
        for (int p = 0; p < SK / 4; p++) idxs[p] = irow[p * 4 + g];

        float mx = -INFINITY, sm = 0.f;
#pragma unroll
        for (int b = 0; b < 2; b++) {
            float4 kv[5];
#pragma unroll
            for (int i = 0; i < 5; i++)
                kv[i] = reinterpret_cast<const float4*>(Kbh + (size_t)idxs[b * 5 + i] * DD)[e];
            float dd[5];
#pragma unroll
            for (int i = 0; i < 5; i++)
                dd[i] = q.x * kv[i].x + q.y * kv[i].y + q.z * kv[i].z + q.w * kv[i].w;
#pragma unroll
            for (int i = 0; i < 5; i++) {
                float d = dd[i];
                d += __shfl_xor(d, 1);
                d += __shfl_xor(d, 2);
                d += __shfl_xor(d, 4);
                d += __shfl_xor(d, 8);
                mx = fmaxf(mx, d);
                sm += d;
            }
        }
        mx = fmaxf(mx, __shfl_xor(mx, 16));
        mx = fmaxf(mx, __shfl_xor(mx, 32));
        sm += __shfl_xor(sm, 16);
        sm += __shfl_xor(sm, 32);
        if (lane == 0) M[wid] = mx - sm * (1.0f / (float)LL);
    } else {
        // ---- k4a body ----
        __shared__ float4 part[16][16];
        int blk = bid - K1_BLOCKS;
        int t = threadIdx.x;
        int d4 = t & 15, rg = t >> 4;
        const float4* v4 = reinterpret_cast<const float4*>(V) + (size_t)blk * 32 * 16 + (size_t)rg * 2 * 16 + d4;
        float4 a = v4[0], b = v4[16];
        part[rg][d4] = f4add(a, b);
        __syncthreads();
#pragma unroll
        for (int step = 8; step; step >>= 1) {
            if (rg < step) part[rg][d4] = f4add(part[rg][d4], part[rg + step][d4]);
            __syncthreads();
        }
        if (rg == 0)
            reinterpret_cast<float4*>(sub)[(size_t)blk * 16 + d4] = part[0][d4];
    }
}

// ================= F2: [k2 || k4b_scan] =================
// blocks [0,32): k2 top-40 (one wave, register-resident, no barriers)
// blocks [32, 2080): k4b — inclusive cumsum of V into out (needs sub only)
__global__ __launch_bounds__(256) void f2_topk_scan(const float* __restrict__ M,
                                                    int* __restrict__ Mtop,
                                                    const float* __restrict__ V,
                                                    const float* __restrict__ sub,
                                                    float* __restrict__ out) {
    int bid = blockIdx.x;
    if (bid < BHN) {
        // ---- k2 body: only wave 0 works; no barriers on this path ----
        int lane = threadIdx.x;
        if (lane >= 64) return;
        int bh = bid;
        const float* Mb = M + (size_t)bh * LL;
        unsigned long long key[32];
#pragma unroll
        for (int j = 0; j < 32; j++) {
            int i = lane + j * 64;
            unsigned u = __float_as_uint(Mb[i]);
            u = (u & 0x80000000u) ? ~u : (u | 0x80000000u);
            key[j] = ((unsigned long long)u << 32) | (unsigned)(~i);
        }
        unsigned long long winner = 0ull;
        for (int t = 0; t < NT; t++) {
            unsigned long long best = 0ull;
#pragma unroll
            for (int j = 0; j < 32; j++) {
                unsigned long long k = key[j];
                k = (k == winner) ? 0ull : k;
                key[j] = k;
                best = (k > best) ? k : best;
            }
#pragma unroll
            for (int off = 32; off; off >>= 1) {
                unsigned long long o = __shfl_xor(best, off);
                best = (o > best) ? o : best;
            }
            winner = best;
            if (lane == 0) Mtop[bh * NT + t] = (int)(~(unsigned)(best & 0xFFFFFFFFull));
        }
    } else {
        // ---- k4b body: cumsum only (merge/scatter moved to k3b) ----
        __shared__ float4 plds[16][16];
        int blk = bid - BHN;
        int bh = blk >> 6, j = blk & 63;
        int t = threadIdx.x;
        int d4 = t & 15, rg = t >> 4;

        const float4* sub4 = reinterpret_cast<const float4*>(sub) + (size_t)(bh * 64) * 16 + d4;
        float4 off = {0.f, 0.f, 0.f, 0.f};
        for (int p = 0; p < j; p++) off = f4add(off, sub4[(size_t)p * 16]);

        const float4* v4 = reinterpret_cast<const float4*>(V) + (size_t)blk * 32 * 16 + (size_t)rg * 2 * 16 + d4;
        float4 a = v4[0], b = v4[16];
        plds[rg][d4] = f4add(a, b);
        __syncthreads();
        float4 ex = {0.f, 0.f, 0.f, 0.f};
        for (int p = 0; p < rg; p++) ex = f4add(ex, plds[p][d4]);

        float4 r0 = f4add(f4add(off, ex), a);
        float4 r1 = f4add(r0, b);
        float4* o4 = reinterpret_cast<float4*>(out) + (size_t)blk * 32 * 16 + (size_t)rg * 2 * 16 + d4;
        o4[0] = r0;
        o4[16] = r1;
    }
}

// ================= K3a: chunked partial attention (USPL=2, vectorized PV) =================
__global__ __launch_bounds__(256) void k3a_partial(const float* __restrict__ Q,
                                                   const float* __restrict__ K,
                                                   const float* __restrict__ V,
                                                   const int* __restrict__ Mtop,
                                                   float* __restrict__ pm,
                                                   float* __restrict__ psum,
                                                   float* __restrict__ pacc) {
    __shared__ float q_lds[UPB * DD];      // 5 KB
    __shared__ float s_lds[UPB][CHUNK];    // 10 KB
    __shared__ int   qi_lds[UPB];
    int bid = blockIdx.x;
    int swz = (bid & 7) * (BHN * NCH * USPL / 8) + (bid >> 3);   // 1024%8==0
    int bh  = swz >> 5;
    int rem = swz & 31;
    int ch  = rem >> 1;
    int u0  = (rem & 1) * UPB;
    int ck  = ch * CHUNK;
    int tid = threadIdx.x;

    if (tid < UPB) qi_lds[tid] = Mtop[bh * NT + u0 + tid];
    __syncthreads();
    for (int c = tid; c < UPB * 16; c += 256) {
        int u = c >> 4, j = c & 15;
        reinterpret_cast<float4*>(q_lds)[c] =
            reinterpret_cast<const float4*>(Q + ((size_t)bh * LL + qi_lds[u]) * DD)[j];
    }
    __syncthreads();

    // scores: thread pair (half 0/1) per key; K half-row in registers
    int k    = ck + (tid >> 1);
    int half = tid & 1;
    const float4* krow = reinterpret_cast<const float4*>(K + ((size_t)bh * LL + k) * DD) + half * 8;
    float4 kreg[8];
#pragma unroll
    for (int j = 0; j < 8; j++) kreg[j] = krow[j];
#pragma unroll 4
    for (int u = 0; u < UPB; u++) {
        const float4* q4 = reinterpret_cast<const float4*>(q_lds + u * DD) + half * 8;
        float d = 0.f;
#pragma unroll
        for (int j = 0; j < 8; j++) {
            float4 a = q4[j], b = kreg[j];
            d += a.x * b.x + a.y * b.y + a.z * b.z + a.w * b.w;
        }
        d += __shfl_xor(d, 1);
        float s = (k <= qi_lds[u]) ? d * SCALE : -INFINITY;
        if (half == 0) s_lds[u][k - ck] = s;
    }
    __syncthreads();

    // per-u local max + expsum; wave w owns u = w + 4*uu (uu < 5)
    int w = tid >> 6, lane = tid & 63;
#pragma unroll
    for (int uu = 0; uu < UPB / 4; uu++) {
        int u = w + uu * 4;
        float s0 = s_lds[u][lane], s1 = s_lds[u][lane + 64];
        float m = fmaxf(s0, s1);
#pragma unroll
        for (int off = 32; off; off >>= 1) m = fmaxf(m, __shfl_xor(m, off));
        float e0 = (s0 == -INFINITY) ? 0.f : __expf(s0 - m);
        float e1 = (s1 == -INFINITY) ? 0.f : __expf(s1 - m);
        s_lds[u][lane] = e0;
        s_lds[u][lane + 64] = e1;
        float smv = e0 + e1;
#pragma unroll
        for (int off = 32; off; off >>= 1) smv += __shfl_xor(smv, off);
        if (lane == 0) {
            size_t rg = (size_t)bh * NT + u0 + u;
            pm  [rg * NCH + ch] = m;
            psum[rg * NCH + ch] = smv;
        }
    }
    __syncthreads();

    // partial PV, vectorized: lane = (d4 = lane&15, kp = lane>>4).
    // float4 V loads, 4 kk-chains in flight; shfl-reduce across kp at the end.
    int d4 = lane & 15, kp = lane >> 4;
    float4 acc[UPB / 4];
#pragma unroll
    for (int uu = 0; uu < UPB / 4; uu++) acc[uu] = make_float4(0.f, 0.f, 0.f, 0.f);
    const float4* v4 = reinterpret_cast<const float4*>(V + ((size_t)bh * LL + ck) * DD) + d4;
#pragma unroll 4
    for (int kb = 0; kb < CHUNK; kb += 4) {
        int kk = kb + kp;
        float4 v = v4[(size_t)kk * 16];
#pragma unroll
        for (int uu = 0; uu < UPB / 4; uu++) {
            float s = s_lds[w + uu * 4][kk];
            acc[uu].x += s * v.x;
            acc[uu].y += s * v.y;
            acc[uu].z += s * v.z;
            acc[uu].w += s * v.w;
        }
    }
#pragma unroll
    for (int uu = 0; uu < UPB / 4; uu++) {
        float4 a = acc[uu];
        a.x += __shfl_xor(a.x, 16); a.x += __shfl_xor(a.x, 32);
        a.y += __shfl_xor(a.y, 16); a.y += __shfl_xor(a.y, 32);
        a.z += __shfl_xor(a.z, 16); a.z += __shfl_xor(a.z, 32);
        a.w += __shfl_xor(a.w, 16); a.w += __shfl_xor(a.w, 32);
        if (kp == 0) {
            size_t rg = (size_t)bh * NT + u0 + w + uu * 4;
            reinterpret_cast<float4*>(pacc + (rg * NCH + ch) * DD)[d4] = a;
        }
    }
}

// ================= K3b: merge chunk partials, scatter to out (after F2) =================
__global__ __launch_bounds__(64) void k3b_scatter(const float* __restrict__ pm,
                                                  const float* __restrict__ psum,
                                                  const float* __restrict__ pacc,
                                                  const int* __restrict__ Mtop,
                                                  float* __restrict__ out) {
    int row = blockIdx.x;            // bh*NT + u
    int lane = threadIdx.x;          // = d
    int bh = row / NT;
    float pmv[NCH];
    float m = -INFINITY;
#pragma unroll
    for (int i = 0; i < NCH; i++) {
        pmv[i] = pm[(size_t)row * NCH + i];
        m = fmaxf(m, pmv[i]);
    }
    float Z = 0.f, acc = 0.f;
#pragma unroll
    for (int i = 0; i < NCH; i++) {
        float sc = (pmv[i] == -INFINITY) ? 0.f : __expf(pmv[i] - m);
        Z   += psum[(size_t)row * NCH + i] * sc;
        acc += pacc[((size_t)row * NCH + i) * DD + lane] * sc;
    }
    int qi = Mtop[row];
    out[((size_t)bh * LL + qi) * DD + lane] = acc / Z;
}

extern "C" void kernel_launch(void* const* d_in, const int* in_sizes, int n_in,
                              void* d_out, int out_size, void* d_ws, size_t ws_size,
                              hipStream_t stream) {
    const float* Q = (const float*)d_in[0];
    const float* K = (const float*)d_in[1];
    const float* V = (const float*)d_in[2];
    const int* isamp = (const int*)d_in[3];
    float* ws   = (float*)d_ws;
    float* M    = ws + WS_M;
    float* sub  = ws + WS_SUB;
    float* pm   = ws + WS_PM;
    float* psum = ws + WS_PSUM;
    float* pacc = ws + WS_PACC;
    int*   Mtop = (int*)(ws + WS_TOP);
    float* out  = (float*)d_out;

    f1_m_sub    <<<K1_BLOCKS + K4A_BLOCKS, 256, 0, stream>>>(Q, K, isamp, V, M, sub);
    f2_topk_scan<<<BHN + K4B_BLOCKS,       256, 0, stream>>>(M, Mtop, V, sub, out);
    k3a_partial <<<BHN * NCH * USPL,       256, 0, stream>>>(Q, K, V, Mtop, pm, psum, pacc);
    k3b_scatter <<<BHN * NT,                64, 0, stream>>>(pm, psum, pacc, Mtop, out);
}